// Round 22
// baseline (272.718 us; speedup 1.0000x reference)
//
#include <hip/hip_runtime.h>
#include <math.h>

#define B_  256
#define H_  200
#define N_  64
#define D_  640
#define DT_ 256
#define NH_ 10
#define HD_ 64
#define MT_ 13   // 13 m-tiles of 16 cover 208 >= 200
#define MH_ 25600  // M half (B_*H_/2)

typedef __attribute__((ext_vector_type(8))) short bf16x8;
typedef __attribute__((ext_vector_type(4))) float f32x4;

__device__ __forceinline__ float wave_reduce_sum(float v) {
    #pragma unroll
    for (int m = 32; m > 0; m >>= 1) v += __shfl_xor(v, m);
    return v;
}
__device__ __forceinline__ float wave_reduce_max(float v) {
    #pragma unroll
    for (int m = 32; m > 0; m >>= 1) v = fmaxf(v, __shfl_xor(v, m));
    return v;
}
__device__ __forceinline__ float red16_sum(float v) {   // reduce over lane&15 group
    #pragma unroll
    for (int m = 1; m < 16; m <<= 1) v += __shfl_xor(v, m);
    return v;
}
__device__ __forceinline__ float red16_max(float v) {
    #pragma unroll
    for (int m = 1; m < 16; m <<= 1) v = fmaxf(v, __shfl_xor(v, m));
    return v;
}
__device__ __forceinline__ short f2bf(float x) {   // RNE bf16
    unsigned u = __float_as_uint(x);
    unsigned r = (u + 0x7fffu + ((u >> 16) & 1u)) >> 16;
    return (short)r;
}
__device__ __forceinline__ float bf2f(short s) {
    return __uint_as_float(((unsigned)(unsigned short)s) << 16);
}

__device__ __forceinline__ void gload_lds16(const void* g, void* lds) {
    __builtin_amdgcn_global_load_lds(
        (const __attribute__((address_space(1))) void*)g,
        (__attribute__((address_space(3))) void*)lds, 16, 0, 0);
}

// one launch converts weights AND topic activations to bf16
__global__ __launch_bounds__(256) void convert5(
    const float* __restrict__ s0, short* __restrict__ d0, int n0,
    const float* __restrict__ s1, short* __restrict__ d1, int n1,
    const float* __restrict__ s2, short* __restrict__ d2, int n2,
    const float* __restrict__ s3, short* __restrict__ d3, int n3,
    const float* __restrict__ s4, short* __restrict__ d4, int n4)
{
    const int e01 = n0 + n1, e02 = n0 + n1 + n2, e03 = e02 + n3;
    const int total = e03 + n4;
    for (int i = blockIdx.x * 256 + threadIdx.x; i < total; i += gridDim.x * 256) {
        if (i < n0)        d0[i] = f2bf(s0[i]);
        else if (i < e01)  d1[i - n0] = f2bf(s1[i - n0]);
        else if (i < e02)  d2[i - e01] = f2bf(s2[i - e01]);
        else if (i < e03)  d3[i - e02] = f2bf(s3[i - e02]);
        else               d4[i - e03] = f2bf(s4[i - e03]);
    }
}

// Core GEMM tile body, fp32-A (gate path): BM=64, BN=128, BK=64, 4 waves,
// acc[4][2], 32 KB LDS -> 5 blocks/CU. Rule-21 both-sides swizzle.
__device__ __forceinline__ void gemm_tile(
    const float* __restrict__ A, int lda,
    const short* __restrict__ Wb, int ldb,
    const float* __restrict__ bias,
    short* __restrict__ Y, int nkc,
    int row0, int col0,
    float* A_f, short* B_lds, int t)
{
    const int lane = t & 63, w = t >> 6;
    const int wm = w >> 1, wn = w & 1;
    const int r16 = lane & 15, g = lane >> 4;

    f32x4 acc[4][2];
    #pragma unroll
    for (int ct = 0; ct < 4; ++ct) {
        acc[ct][0] = (f32x4){0.f,0.f,0.f,0.f};
        acc[ct][1] = (f32x4){0.f,0.f,0.f,0.f};
    }

    for (int k = 0; k < nkc; ++k) {
        const int k0 = k * 64;
        #pragma unroll
        for (int j = 0; j < 4; ++j) {
            const int u = t + j * 256;
            const int row = u >> 4, jj = u & 15;
            gload_lds16(A + (long)(row0 + row) * lda + k0 + ((jj ^ (row & 7)) << 2),
                        (char*)A_f + u * 16);
        }
        #pragma unroll
        for (int j = 0; j < 4; ++j) {
            const int u = t + j * 256;
            const int col = u >> 3, jj = u & 7;
            gload_lds16(Wb + (long)(col0 + col) * ldb + k0 + ((jj ^ (col & 7)) << 3),
                        (char*)B_lds + u * 16);
        }
        __syncthreads();

        #pragma unroll
        for (int kk = 0; kk < 2; ++kk) {
            bf16x8 a[2];
            #pragma unroll
            for (int rt = 0; rt < 2; ++rt) {
                const int row = wm * 32 + rt * 16 + r16;
                const int s = kk * 8 + g * 2;
                float4 f0 = *(const float4*)(A_f + row * 64 + ((s ^ (row & 7)) << 2));
                float4 f1 = *(const float4*)(A_f + row * 64 + (((s + 1) ^ (row & 7)) << 2));
                bf16x8 av;
                av[0] = f2bf(f0.x); av[1] = f2bf(f0.y); av[2] = f2bf(f0.z); av[3] = f2bf(f0.w);
                av[4] = f2bf(f1.x); av[5] = f2bf(f1.y); av[6] = f2bf(f1.z); av[7] = f2bf(f1.w);
                a[rt] = av;
            }
            #pragma unroll
            for (int ct = 0; ct < 4; ++ct) {
                const int col = wn * 64 + ct * 16 + r16;
                const int sb = kk * 4 + g;
                bf16x8 b = *(const bf16x8*)(B_lds + col * 64 + ((sb ^ (col & 7)) << 3));
                acc[ct][0] = __builtin_amdgcn_mfma_f32_16x16x32_bf16(a[0], b, acc[ct][0], 0, 0, 0);
                acc[ct][1] = __builtin_amdgcn_mfma_f32_16x16x32_bf16(a[1], b, acc[ct][1], 0, 0, 0);
            }
        }
        __syncthreads();
    }

    #pragma unroll
    for (int ct = 0; ct < 4; ++ct) {
        const int col = col0 + wn * 64 + ct * 16 + r16;
        const float bv = bias ? bias[col] : 0.f;
        #pragma unroll
        for (int rt = 0; rt < 2; ++rt)
            #pragma unroll
            for (int i = 0; i < 4; ++i)
                Y[(long)(row0 + wm * 32 + rt * 16 + g * 4 + i) * D_ + col] =
                    f2bf(acc[ct][rt][i] + bv);
    }
}

// standalone GEMM (gate path) — unchanged from r21 best config
__global__ __launch_bounds__(256, 5) void gemm_bt(
    const float* __restrict__ A, int lda,
    const short* __restrict__ Wb, int ldb,
    const float* __restrict__ bias,
    short* __restrict__ Y, int nkc)
{
    __shared__ float A_f[64 * 64];      // 16 KB
    __shared__ short B_lds[128 * 64];   // 16 KB
    const int lb = (blockIdx.x & 7) * ((int)gridDim.x >> 3) + (blockIdx.x >> 3);
    gemm_tile(A, lda, Wb, ldb, bias, Y, nkc,
              (lb / 5) * 64, (lb % 5) * 128, A_f, B_lds, threadIdx.x);
}

// Proj tile body, bf16-A, BK=128 (K=256 -> 2 chunks, 4 barriers/block,
// no f2bf in the loop). A [64][128] bf16 16 KB + B [128][128] 32 KB = 48 KB.
// 16-granule XOR swizzle (jj ^ (row&15)) -> 2-way bank alias on reads.
__device__ __forceinline__ void gemm_tile_bb(
    const short* __restrict__ Ab,
    const short* __restrict__ Wb,
    const float* __restrict__ bias,
    short* __restrict__ Y, float* __restrict__ qss,
    int row0, int col0,
    short* A_l, short* B_l, int t)
{
    const int lane = t & 63, w = t >> 6;
    const int wm = w >> 1, wn = w & 1;
    const int r16 = lane & 15, g = lane >> 4;

    f32x4 acc[4][2];
    #pragma unroll
    for (int ct = 0; ct < 4; ++ct) {
        acc[ct][0] = (f32x4){0.f,0.f,0.f,0.f};
        acc[ct][1] = (f32x4){0.f,0.f,0.f,0.f};
    }

    #pragma unroll
    for (int k = 0; k < 2; ++k) {
        const int k0 = k * 128;
        // A: 1024 granules (16B = 8 bf16), 4/thread
        #pragma unroll
        for (int j = 0; j < 4; ++j) {
            const int u = t + j * 256;
            const int row = u >> 4, jj = u & 15;
            gload_lds16(Ab + (long)(row0 + row) * DT_ + k0 + ((jj ^ (row & 15)) << 3),
                        (char*)A_l + u * 16);
        }
        // B: 2048 granules, 8/thread
        #pragma unroll
        for (int j = 0; j < 8; ++j) {
            const int u = t + j * 256;
            const int col = u >> 4, jj = u & 15;
            gload_lds16(Wb + (long)(col0 + col) * DT_ + k0 + ((jj ^ (col & 15)) << 3),
                        (char*)B_l + u * 16);
        }
        __syncthreads();

        #pragma unroll
        for (int kk = 0; kk < 4; ++kk) {
            bf16x8 a[2];
            #pragma unroll
            for (int rt = 0; rt < 2; ++rt) {
                const int row = wm * 32 + rt * 16 + r16;
                const int s = kk * 4 + g;
                a[rt] = *(const bf16x8*)(A_l + (row * 16 + (s ^ (row & 15))) * 8);
            }
            #pragma unroll
            for (int ct = 0; ct < 4; ++ct) {
                const int col = wn * 64 + ct * 16 + r16;
                const int sb = kk * 4 + g;
                bf16x8 b = *(const bf16x8*)(B_l + (col * 16 + (sb ^ (col & 15))) * 8);
                acc[ct][0] = __builtin_amdgcn_mfma_f32_16x16x32_bf16(a[0], b, acc[ct][0], 0, 0, 0);
                acc[ct][1] = __builtin_amdgcn_mfma_f32_16x16x32_bf16(a[1], b, acc[ct][1], 0, 0, 0);
            }
        }
        __syncthreads();
    }

    float ps[2][4];
    #pragma unroll
    for (int rt = 0; rt < 2; ++rt)
        #pragma unroll
        for (int i = 0; i < 4; ++i) ps[rt][i] = 0.f;

    #pragma unroll
    for (int ct = 0; ct < 4; ++ct) {
        const int col = col0 + wn * 64 + ct * 16 + r16;
        const float bv = bias ? bias[col] : 0.f;
        #pragma unroll
        for (int rt = 0; rt < 2; ++rt)
            #pragma unroll
            for (int i = 0; i < 4; ++i) {
                const short ob = f2bf(acc[ct][rt][i] + bv);
                Y[(long)(row0 + wm * 32 + rt * 16 + g * 4 + i) * D_ + col] = ob;
                if (qss) { const float of = bf2f(ob); ps[rt][i] += of * of; }
            }
    }
    if (qss) {
        const int strip = col0 >> 7;
        #pragma unroll
        for (int rt = 0; rt < 2; ++rt)
            #pragma unroll
            for (int i = 0; i < 4; ++i) {
                const float s = red16_sum(ps[rt][i]);
                if (r16 == 0) {
                    const int row = row0 + wm * 32 + rt * 16 + g * 4 + i;
                    qss[(long)row * 10 + strip * 2 + wn] = s;
                }
            }
    }
}

// merged Q-proj + K-proj (bf16 inputs): one grid, uniform branch.
#define NQB 1280   // Q: 256 row-panels x 5 col-strips
#define NKB 4000   // K: 800 row-panels x 5 col-strips
__global__ __launch_bounds__(256, 3) void proj2(
    const short* __restrict__ Atq, const short* __restrict__ Wqb,
    const float* __restrict__ bq, short* __restrict__ Yq, float* __restrict__ qss,
    const short* __restrict__ Atk, const short* __restrict__ Wkb,
    const float* __restrict__ bk, short* __restrict__ Yk)
{
    __shared__ short A_l[64 * 128];    // 16 KB
    __shared__ short B_l[128 * 128];   // 32 KB
    const int lb = (blockIdx.x & 7) * ((int)gridDim.x >> 3) + (blockIdx.x >> 3);
    if (lb < NQB) {
        gemm_tile_bb(Atq, Wqb, bq, Yq, qss,
                     (lb / 5) * 64, (lb % 5) * 128, A_l, B_l, threadIdx.x);
    } else {
        const int kb = lb - NQB;
        gemm_tile_bb(Atk, Wkb, bk, Yk, nullptr,
                     (kb / 5) * 64, (kb % 5) * 128, A_l, B_l, threadIdx.x);
    }
}

// attn2 v4 (unchanged): K head-slices staged in LDS, double-buffered;
// query norms from qss partials.
__global__ __launch_bounds__(512, 2) void attn2(
    const short* __restrict__ Qb, const short* __restrict__ Kb,
    const float* __restrict__ qss,
    float* __restrict__ aw, float* __restrict__ out_tail)
{
    __shared__ short K_l[2][2][208 * 64];   // [half][dbuf] 4 x 26.6 KB
    __shared__ float qw_l[N_];
    __shared__ float aggp[8][MT_ * 16];
    __shared__ float red2[2];
    const int t = threadIdx.x;
    const int lane = t & 63, w = t >> 6;
    const int wm = w & 3, hh = w >> 2;
    const int r16 = lane & 15, g = lane >> 4;
    const int b = blockIdx.x;
    const int tt = t & 255;
    const int half = t >> 8;   // == hh

    auto STAGE_K = [&](int bi, int hi) {
        const int h = half * 5 + hi;
        #pragma unroll
        for (int j = 0; j < 7; ++j) {
            const int u = tt + j * 256;
            if (u < 208 * 8) {
                const int row = u >> 3, jg = u & 7;
                gload_lds16(Kb + ((long)(b * H_) + row) * D_ + h * HD_ +
                                ((jg ^ (row & 7)) << 3),
                            (char*)K_l[half][bi] + u * 16);
            }
        }
    };

    STAGE_K(0, 0);   // drained by the barrier below

    // qw from precomputed sumsq partials (10 floats per row)
    if (w == 0) {
        const float* qp = qss + ((long)(b * N_ + lane)) * 10;
        float ss = 0.f;
        #pragma unroll
        for (int j = 0; j < 10; ++j) ss += qp[j];
        float v = sqrtf(ss);
        float mx = wave_reduce_max(v);
        float e = __expf(v - mx);
        float s = wave_reduce_sum(e);
        qw_l[lane] = e / s;
    }
    __syncthreads();   // qw ready + K_l[*][0] staged

    float qwr[4];
    #pragma unroll
    for (int i = 0; i < 4; ++i) qwr[i] = qw_l[wm * 16 + g * 4 + i];

    const float inv_scale = 0.0395284707521047f;   // 1/sqrt(640)
    float aggl[MT_];
    #pragma unroll
    for (int mt = 0; mt < MT_; ++mt) aggl[mt] = 0.f;

    for (int hi = 0; hi < 5; ++hi) {
        const int h = hh * 5 + hi;
        if (hi + 1 < 5) STAGE_K((hi + 1) & 1, hi + 1);   // issue before compute

        const short* kl = K_l[hh][hi & 1];
        const short* qbase = Qb + ((long)(b * N_ + wm * 16 + r16)) * D_ + h * HD_ + g * 8;
        bf16x8 a0 = *(const bf16x8*)(qbase);
        bf16x8 a1 = *(const bf16x8*)(qbase + 32);
        bf16x8 kb0[MT_], kb1[MT_];
        #pragma unroll
        for (int mt = 0; mt < MT_; ++mt) {
            const int row = mt * 16 + r16;
            const int s0 = g ^ (row & 7);
            const int s1 = (g + 4) ^ (row & 7);
            kb0[mt] = *(const bf16x8*)(kl + row * 64 + s0 * 8);
            kb1[mt] = *(const bf16x8*)(kl + row * 64 + s1 * 8);
        }
        f32x4 acc[MT_];
        #pragma unroll
        for (int mt = 0; mt < MT_; ++mt) {
            f32x4 z = {0.f,0.f,0.f,0.f};
            z = __builtin_amdgcn_mfma_f32_16x16x32_bf16(a0, kb0[mt], z, 0, 0, 0);
            z = __builtin_amdgcn_mfma_f32_16x16x32_bf16(a1, kb1[mt], z, 0, 0, 0);
            acc[mt] = z;
        }
        const bool tailok = (r16 < 8);   // mt==12 valid only for m<200
        float mx[4] = {-INFINITY, -INFINITY, -INFINITY, -INFINITY};
        #pragma unroll
        for (int mt = 0; mt < MT_; ++mt) {
            const bool valid = (mt < 12) || tailok;
            #pragma unroll
            for (int i = 0; i < 4; ++i)
                if (valid) mx[i] = fmaxf(mx[i], acc[mt][i]);
        }
        #pragma unroll
        for (int i = 0; i < 4; ++i) mx[i] = red16_max(mx[i]);
        float sum[4] = {0.f, 0.f, 0.f, 0.f};
        #pragma unroll
        for (int mt = 0; mt < MT_; ++mt) {
            const bool valid = (mt < 12) || tailok;
            #pragma unroll
            for (int i = 0; i < 4; ++i) {
                float e = valid ? __expf((acc[mt][i] - mx[i]) * inv_scale) : 0.f;
                acc[mt][i] = e;
                sum[i] += e;
            }
        }
        float fct[4];
        #pragma unroll
        for (int i = 0; i < 4; ++i) fct[i] = qwr[i] / red16_sum(sum[i]);
        #pragma unroll
        for (int mt = 0; mt < MT_; ++mt)
            aggl[mt] += acc[mt][0] * fct[0] + acc[mt][1] * fct[1]
                      + acc[mt][2] * fct[2] + acc[mt][3] * fct[3];

        __syncthreads();   // drains STAGE(hi+1); frees buf[hi&1] for hi+2
    }

    #pragma unroll
    for (int mt = 0; mt < MT_; ++mt) {
        aggl[mt] += __shfl_xor(aggl[mt], 16);
        aggl[mt] += __shfl_xor(aggl[mt], 32);
    }
    if (g == 0) {
        #pragma unroll
        for (int mt = 0; mt < MT_; ++mt) aggp[w][mt * 16 + r16] = aggl[mt];
    }
    __syncthreads();
    if (t < MT_ * 16) {
        float v = 0.f;
        #pragma unroll
        for (int j = 0; j < 8; ++j) v += aggp[j][t];
        aggp[0][t] = v;
    }
    __syncthreads();
    if (w == 0) {
        float v0 = aggp[0][lane], v1 = aggp[0][lane + 64], v2 = aggp[0][lane + 128];
        const bool has3 = lane < (H_ - 192);
        float v3 = has3 ? aggp[0][lane + 192] : -INFINITY;
        float mx = wave_reduce_max(fmaxf(fmaxf(v0, v1), fmaxf(v2, v3)));
        float s = __expf(v0 - mx) + __expf(v1 - mx) + __expf(v2 - mx)
                + (has3 ? __expf(v3 - mx) : 0.f);
        s = wave_reduce_sum(s);
        if (lane == 0) { red2[0] = mx; red2[1] = s; }
    }
    __syncthreads();
    if (t < H_) {
        float v = __expf(aggp[0][t] - red2[0]) / red2[1];
        aw[b * H_ + t] = v;
        out_tail[b * H_ + t] = v;
    }
}

// blendln (at HBM roofline): z = aw*y + bg; gate = sigmoid(z);
// o = cl*(1 + gt*(aw-1)); LN. One wave per row; 4 rows per block.
__global__ __launch_bounds__(256) void blendln(
    const float* __restrict__ cl, const short* __restrict__ Z,
    const float* __restrict__ aw, const float* __restrict__ bg,
    const float* __restrict__ gamma, const float* __restrict__ beta,
    float* __restrict__ out)
{
    const int t = threadIdx.x;
    const int lane = t & 63, w = t >> 6;
    const int row = blockIdx.x * 4 + w;
    const float awr = aw[row];
    const long base = (long)row * D_;

    float o[10];
    float s = 0.f, sq = 0.f;
    #pragma unroll
    for (int i = 0; i < 10; ++i) {
        const int col = lane + 64 * i;
        const float y = bf2f(Z[base + col]);
        const float c = cl[base + col];
        const float z = awr * y + bg[col];
        const float gt = 1.f / (1.f + __expf(-z));
        const float ov = c * (1.f + gt * (awr - 1.f));
        o[i] = ov; s += ov; sq += ov * ov;
    }
    s  = wave_reduce_sum(s);
    sq = wave_reduce_sum(sq);
    const float mu  = s * (1.f / D_);
    const float var = sq * (1.f / D_) - mu * mu;
    const float ri  = 1.0f / sqrtf(var + 1e-5f);
    #pragma unroll
    for (int i = 0; i < 10; ++i) {
        const int col = lane + 64 * i;
        out[base + col] = (o[i] - mu) * ri * gamma[col] + beta[col];
    }
}

extern "C" void kernel_launch(void* const* d_in, const int* in_sizes, int n_in,
                              void* d_out, int out_size, void* d_ws, size_t ws_size,
                              hipStream_t stream) {
    const float* clicked_news   = (const float*)d_in[0];   // [B,H,D]
    const float* clicked_topics = (const float*)d_in[1];   // [B,H,Dt]
    const float* cand_topics    = (const float*)d_in[2];   // [B,N,Dt]
    const float* Wq = (const float*)d_in[3];
    const float* bq = (const float*)d_in[4];
    const float* Wk = (const float*)d_in[5];
    const float* bk = (const float*)d_in[6];
    // d_in[7], d_in[8] = Wv, bv: dead code w.r.t. outputs
    const float* Wg = (const float*)d_in[9];
    const float* bg = (const float*)d_in[10];
    const float* ln_gamma = (const float*)d_in[11];
    const float* ln_beta  = (const float*)d_in[12];

    float* out = (float*)d_out;
    float* ws  = (float*)d_ws;

    // ws layout: aw, weights, qss, Atq, Qb, Atk.
    // Z (gate output, 32.8 MB) aliases Qb and extends into Atk — both dead
    // by the time the gate GEMM runs (after attn2).
    float* aw   = ws;                                    // B*H floats
    short* Wq_b = (short*)(aw + (long)B_ * H_);          // 163,840 sh
    short* Wk_b = Wq_b + (long)D_ * DT_;                 // 163,840 sh
    short* Wg_b = Wk_b + (long)D_ * DT_;                 // 409,600 sh
    float* qss  = (float*)(Wg_b + (long)D_ * D_);        // B*N*10 floats
    short* Atq  = (short*)(qss + (long)B_ * N_ * 10);    // 4,194,304 sh (cand bf16)
    short* Qb   = Atq + (long)B_ * N_ * DT_;             // 10,485,760 sh
    short* Atk  = Qb + (long)B_ * N_ * D_;               // 13,107,200 sh (ctop bf16)
    short* Z    = Qb;                                    // 16,384,000 sh (aliases Qb+Atk)
    // Kb (bf16) at start of d_out: read by attn2, overwritten by blendln.
    short* Kb = (short*)d_out;
    float* out_tail = out + (long)B_ * H_ * D_;          // attn_weights_agg

    convert5<<<2048, 256, 0, stream>>>(
        Wq, Wq_b, D_ * DT_,
        Wk, Wk_b, D_ * DT_,
        Wg, Wg_b, D_ * D_,
        cand_topics, Atq, B_ * N_ * DT_,
        clicked_topics, Atk, B_ * H_ * DT_);

    // merged Q-proj (+qss) and K-proj: 1280 + 4000 = 5280 blocks (÷8 ok)
    proj2<<<NQB + NKB, 256, 0, stream>>>(Atq, Wq_b, bq, Qb, qss,
                                         Atk, Wk_b, bk, Kb);
    attn2<<<B_, 512, 0, stream>>>(Qb, Kb, qss, aw, out_tail);

    for (int h = 0; h < 2; ++h) {
        const long off = (long)h * MH_;
        // gate GEMM half: 400 x 5 = 2000 blocks (÷8 ok)
        gemm_bt<<<2000, 256, 0, stream>>>(clicked_news + off * D_, D_,
                                          Wg_b, D_, nullptr, Z, 10);
        blendln<<<MH_ / 4, 256, 0, stream>>>(
            clicked_news + off * D_, Z, aw + off, bg, ln_gamma, ln_beta,
            out + off * D_);
    }
}

// Round 23
// 263.682 us; speedup vs baseline: 1.0343x; 1.0343x over previous
//
#include <hip/hip_runtime.h>
#include <math.h>

#define B_  256
#define H_  200
#define N_  64
#define D_  640
#define DT_ 256
#define NH_ 10
#define HD_ 64
#define MT_ 13   // 13 m-tiles of 16 cover 208 >= 200
#define MH_ 25600  // M half (B_*H_/2)

typedef __attribute__((ext_vector_type(8))) short bf16x8;
typedef __attribute__((ext_vector_type(4))) float f32x4;

__device__ __forceinline__ float wave_reduce_sum(float v) {
    #pragma unroll
    for (int m = 32; m > 0; m >>= 1) v += __shfl_xor(v, m);
    return v;
}
__device__ __forceinline__ float wave_reduce_max(float v) {
    #pragma unroll
    for (int m = 32; m > 0; m >>= 1) v = fmaxf(v, __shfl_xor(v, m));
    return v;
}
__device__ __forceinline__ float red16_sum(float v) {   // reduce over lane&15 group
    #pragma unroll
    for (int m = 1; m < 16; m <<= 1) v += __shfl_xor(v, m);
    return v;
}
__device__ __forceinline__ float red16_max(float v) {
    #pragma unroll
    for (int m = 1; m < 16; m <<= 1) v = fmaxf(v, __shfl_xor(v, m));
    return v;
}
__device__ __forceinline__ short f2bf(float x) {   // RNE bf16
    unsigned u = __float_as_uint(x);
    unsigned r = (u + 0x7fffu + ((u >> 16) & 1u)) >> 16;
    return (short)r;
}
__device__ __forceinline__ float bf2f(short s) {
    return __uint_as_float(((unsigned)(unsigned short)s) << 16);
}

__device__ __forceinline__ void gload_lds16(const void* g, void* lds) {
    __builtin_amdgcn_global_load_lds(
        (const __attribute__((address_space(1))) void*)g,
        (__attribute__((address_space(3))) void*)lds, 16, 0, 0);
}

// one launch converts all three weight matrices to bf16
__global__ __launch_bounds__(256) void convert3(
    const float* __restrict__ s0, short* __restrict__ d0, int n0,
    const float* __restrict__ s1, short* __restrict__ d1, int n1,
    const float* __restrict__ s2, short* __restrict__ d2, int n2)
{
    const int total = n0 + n1 + n2;
    for (int i = blockIdx.x * 256 + threadIdx.x; i < total; i += gridDim.x * 256) {
        if (i < n0)            d0[i] = f2bf(s0[i]);
        else if (i < n0 + n1)  d1[i - n0] = f2bf(s1[i - n0]);
        else                   d2[i - n0 - n1] = f2bf(s2[i - n0 - n1]);
    }
}

// Core GEMM tile body (r17/r19 structure): BM=64, BN=128, BK=64,
// 256 threads = 4 waves, acc[4][2]. 32 KB LDS -> 5 blocks/CU.
// Rule-21 both-sides swizzle. Computes Y[row0..+64, col0..+128] and
// optionally qss partials (Q-proj query norms).
__device__ __forceinline__ void gemm_tile(
    const float* __restrict__ A, int lda,
    const short* __restrict__ Wb, int ldb,
    const float* __restrict__ bias,
    short* __restrict__ Y, int nkc, float* __restrict__ qss,
    int row0, int col0,
    float* A_f, short* B_lds, int t)
{
    const int lane = t & 63, w = t >> 6;
    const int wm = w >> 1, wn = w & 1;
    const int r16 = lane & 15, g = lane >> 4;

    f32x4 acc[4][2];
    #pragma unroll
    for (int ct = 0; ct < 4; ++ct) {
        acc[ct][0] = (f32x4){0.f,0.f,0.f,0.f};
        acc[ct][1] = (f32x4){0.f,0.f,0.f,0.f};
    }

    for (int k = 0; k < nkc; ++k) {
        const int k0 = k * 64;
        #pragma unroll
        for (int j = 0; j < 4; ++j) {
            const int u = t + j * 256;
            const int row = u >> 4, jj = u & 15;
            gload_lds16(A + (long)(row0 + row) * lda + k0 + ((jj ^ (row & 7)) << 2),
                        (char*)A_f + u * 16);
        }
        #pragma unroll
        for (int j = 0; j < 4; ++j) {
            const int u = t + j * 256;
            const int col = u >> 3, jj = u & 7;
            gload_lds16(Wb + (long)(col0 + col) * ldb + k0 + ((jj ^ (col & 7)) << 3),
                        (char*)B_lds + u * 16);
        }
        __syncthreads();

        #pragma unroll
        for (int kk = 0; kk < 2; ++kk) {
            bf16x8 a[2];
            #pragma unroll
            for (int rt = 0; rt < 2; ++rt) {
                const int row = wm * 32 + rt * 16 + r16;
                const int s = kk * 8 + g * 2;
                float4 f0 = *(const float4*)(A_f + row * 64 + ((s ^ (row & 7)) << 2));
                float4 f1 = *(const float4*)(A_f + row * 64 + (((s + 1) ^ (row & 7)) << 2));
                bf16x8 av;
                av[0] = f2bf(f0.x); av[1] = f2bf(f0.y); av[2] = f2bf(f0.z); av[3] = f2bf(f0.w);
                av[4] = f2bf(f1.x); av[5] = f2bf(f1.y); av[6] = f2bf(f1.z); av[7] = f2bf(f1.w);
                a[rt] = av;
            }
            #pragma unroll
            for (int ct = 0; ct < 4; ++ct) {
                const int col = wn * 64 + ct * 16 + r16;
                const int sb = kk * 4 + g;
                bf16x8 b = *(const bf16x8*)(B_lds + col * 64 + ((sb ^ (col & 7)) << 3));
                acc[ct][0] = __builtin_amdgcn_mfma_f32_16x16x32_bf16(a[0], b, acc[ct][0], 0, 0, 0);
                acc[ct][1] = __builtin_amdgcn_mfma_f32_16x16x32_bf16(a[1], b, acc[ct][1], 0, 0, 0);
            }
        }
        __syncthreads();
    }

    float ps[2][4];
    #pragma unroll
    for (int rt = 0; rt < 2; ++rt)
        #pragma unroll
        for (int i = 0; i < 4; ++i) ps[rt][i] = 0.f;

    #pragma unroll
    for (int ct = 0; ct < 4; ++ct) {
        const int col = col0 + wn * 64 + ct * 16 + r16;
        const float bv = bias ? bias[col] : 0.f;
        #pragma unroll
        for (int rt = 0; rt < 2; ++rt)
            #pragma unroll
            for (int i = 0; i < 4; ++i) {
                const short ob = f2bf(acc[ct][rt][i] + bv);
                Y[(long)(row0 + wm * 32 + rt * 16 + g * 4 + i) * D_ + col] = ob;
                if (qss) { const float of = bf2f(ob); ps[rt][i] += of * of; }
            }
    }
    if (qss) {
        const int strip = col0 >> 7;
        #pragma unroll
        for (int rt = 0; rt < 2; ++rt)
            #pragma unroll
            for (int i = 0; i < 4; ++i) {
                const float s = red16_sum(ps[rt][i]);
                if (r16 == 0) {
                    const int row = row0 + wm * 32 + rt * 16 + g * 4 + i;
                    qss[(long)row * 10 + strip * 2 + wn] = s;
                }
            }
    }
}

// standalone GEMM (gate path)
__global__ __launch_bounds__(256, 5) void gemm_bt(
    const float* __restrict__ A, int lda,
    const short* __restrict__ Wb, int ldb,
    const float* __restrict__ bias,
    short* __restrict__ Y, int nkc)
{
    __shared__ float A_f[64 * 64];      // 16 KB
    __shared__ short B_lds[128 * 64];   // 16 KB
    const int lb = (blockIdx.x & 7) * ((int)gridDim.x >> 3) + (blockIdx.x >> 3);
    gemm_tile(A, lda, Wb, ldb, bias, Y, nkc, nullptr,
              (lb / 5) * 64, (lb % 5) * 128, A_f, B_lds, threadIdx.x);
}

// merged Q-proj + K-proj: one grid (NQB + NKB blocks), uniform branch.
#define NQB 1280   // Q: 256 row-panels x 5 col-strips
#define NKB 4000   // K: 800 row-panels x 5 col-strips
__global__ __launch_bounds__(256, 5) void proj2(
    const float* __restrict__ Aq, const short* __restrict__ Wqb,
    const float* __restrict__ bq, short* __restrict__ Yq, float* __restrict__ qss,
    const float* __restrict__ Ak, const short* __restrict__ Wkb,
    const float* __restrict__ bk, short* __restrict__ Yk)
{
    __shared__ float A_f[64 * 64];
    __shared__ short B_lds[128 * 64];
    const int lb = (blockIdx.x & 7) * ((int)gridDim.x >> 3) + (blockIdx.x >> 3);
    if (lb < NQB) {
        gemm_tile(Aq, DT_, Wqb, DT_, bq, Yq, 4, qss,
                  (lb / 5) * 64, (lb % 5) * 128, A_f, B_lds, threadIdx.x);
    } else {
        const int kb = lb - NQB;
        gemm_tile(Ak, DT_, Wkb, DT_, bk, Yk, 4, nullptr,
                  (kb / 5) * 64, (kb % 5) * 128, A_f, B_lds, threadIdx.x);
    }
}

// attn2 v4: K head-slices staged in LDS (double-buffered per half-block);
// query norms come precomputed from Q-proj (qss partials) -> no Qb scan.
__global__ __launch_bounds__(512, 2) void attn2(
    const short* __restrict__ Qb, const short* __restrict__ Kb,
    const float* __restrict__ qss,
    float* __restrict__ aw, float* __restrict__ out_tail)
{
    __shared__ short K_l[2][2][208 * 64];   // [half][dbuf] 4 x 26.6 KB
    __shared__ float qw_l[N_];
    __shared__ float aggp[8][MT_ * 16];
    __shared__ float red2[2];
    const int t = threadIdx.x;
    const int lane = t & 63, w = t >> 6;
    const int wm = w & 3, hh = w >> 2;
    const int r16 = lane & 15, g = lane >> 4;
    const int b = blockIdx.x;
    const int tt = t & 255;
    const int half = t >> 8;   // == hh

    auto STAGE_K = [&](int bi, int hi) {
        const int h = half * 5 + hi;
        #pragma unroll
        for (int j = 0; j < 7; ++j) {
            const int u = tt + j * 256;
            if (u < 208 * 8) {
                const int row = u >> 3, jg = u & 7;
                gload_lds16(Kb + ((long)(b * H_) + row) * D_ + h * HD_ +
                                ((jg ^ (row & 7)) << 3),
                            (char*)K_l[half][bi] + u * 16);
            }
        }
    };

    STAGE_K(0, 0);   // drained by the barrier below

    // qw from precomputed sumsq partials (10 floats per row)
    if (w == 0) {
        const float* qp = qss + ((long)(b * N_ + lane)) * 10;
        float ss = 0.f;
        #pragma unroll
        for (int j = 0; j < 10; ++j) ss += qp[j];
        float v = sqrtf(ss);
        float mx = wave_reduce_max(v);
        float e = __expf(v - mx);
        float s = wave_reduce_sum(e);
        qw_l[lane] = e / s;
    }
    __syncthreads();   // qw ready + K_l[*][0] staged

    float qwr[4];
    #pragma unroll
    for (int i = 0; i < 4; ++i) qwr[i] = qw_l[wm * 16 + g * 4 + i];

    const float inv_scale = 0.0395284707521047f;   // 1/sqrt(640)
    float aggl[MT_];
    #pragma unroll
    for (int mt = 0; mt < MT_; ++mt) aggl[mt] = 0.f;

    for (int hi = 0; hi < 5; ++hi) {
        const int h = hh * 5 + hi;
        if (hi + 1 < 5) STAGE_K((hi + 1) & 1, hi + 1);   // issue before compute

        const short* kl = K_l[hh][hi & 1];
        const short* qbase = Qb + ((long)(b * N_ + wm * 16 + r16)) * D_ + h * HD_ + g * 8;
        bf16x8 a0 = *(const bf16x8*)(qbase);
        bf16x8 a1 = *(const bf16x8*)(qbase + 32);
        bf16x8 kb0[MT_], kb1[MT_];
        #pragma unroll
        for (int mt = 0; mt < MT_; ++mt) {
            const int row = mt * 16 + r16;
            const int s0 = g ^ (row & 7);
            const int s1 = (g + 4) ^ (row & 7);
            kb0[mt] = *(const bf16x8*)(kl + row * 64 + s0 * 8);
            kb1[mt] = *(const bf16x8*)(kl + row * 64 + s1 * 8);
        }
        f32x4 acc[MT_];
        #pragma unroll
        for (int mt = 0; mt < MT_; ++mt) {
            f32x4 z = {0.f,0.f,0.f,0.f};
            z = __builtin_amdgcn_mfma_f32_16x16x32_bf16(a0, kb0[mt], z, 0, 0, 0);
            z = __builtin_amdgcn_mfma_f32_16x16x32_bf16(a1, kb1[mt], z, 0, 0, 0);
            acc[mt] = z;
        }
        const bool tailok = (r16 < 8);   // mt==12 valid only for m<200
        float mx[4] = {-INFINITY, -INFINITY, -INFINITY, -INFINITY};
        #pragma unroll
        for (int mt = 0; mt < MT_; ++mt) {
            const bool valid = (mt < 12) || tailok;
            #pragma unroll
            for (int i = 0; i < 4; ++i)
                if (valid) mx[i] = fmaxf(mx[i], acc[mt][i]);
        }
        #pragma unroll
        for (int i = 0; i < 4; ++i) mx[i] = red16_max(mx[i]);
        float sum[4] = {0.f, 0.f, 0.f, 0.f};
        #pragma unroll
        for (int mt = 0; mt < MT_; ++mt) {
            const bool valid = (mt < 12) || tailok;
            #pragma unroll
            for (int i = 0; i < 4; ++i) {
                float e = valid ? __expf((acc[mt][i] - mx[i]) * inv_scale) : 0.f;
                acc[mt][i] = e;
                sum[i] += e;
            }
        }
        float fct[4];
        #pragma unroll
        for (int i = 0; i < 4; ++i) fct[i] = qwr[i] / red16_sum(sum[i]);
        #pragma unroll
        for (int mt = 0; mt < MT_; ++mt)
            aggl[mt] += acc[mt][0] * fct[0] + acc[mt][1] * fct[1]
                      + acc[mt][2] * fct[2] + acc[mt][3] * fct[3];

        __syncthreads();   // drains STAGE(hi+1); frees buf[hi&1] for hi+2
    }

    #pragma unroll
    for (int mt = 0; mt < MT_; ++mt) {
        aggl[mt] += __shfl_xor(aggl[mt], 16);
        aggl[mt] += __shfl_xor(aggl[mt], 32);
    }
    if (g == 0) {
        #pragma unroll
        for (int mt = 0; mt < MT_; ++mt) aggp[w][mt * 16 + r16] = aggl[mt];
    }
    __syncthreads();
    if (t < MT_ * 16) {
        float v = 0.f;
        #pragma unroll
        for (int j = 0; j < 8; ++j) v += aggp[j][t];
        aggp[0][t] = v;
    }
    __syncthreads();
    if (w == 0) {
        float v0 = aggp[0][lane], v1 = aggp[0][lane + 64], v2 = aggp[0][lane + 128];
        const bool has3 = lane < (H_ - 192);
        float v3 = has3 ? aggp[0][lane + 192] : -INFINITY;
        float mx = wave_reduce_max(fmaxf(fmaxf(v0, v1), fmaxf(v2, v3)));
        float s = __expf(v0 - mx) + __expf(v1 - mx) + __expf(v2 - mx)
                + (has3 ? __expf(v3 - mx) : 0.f);
        s = wave_reduce_sum(s);
        if (lane == 0) { red2[0] = mx; red2[1] = s; }
    }
    __syncthreads();
    if (t < H_) {
        float v = __expf(aggp[0][t] - red2[0]) / red2[1];
        aw[b * H_ + t] = v;
        out_tail[b * H_ + t] = v;
    }
}

// blendln (at HBM roofline): z = aw*y + bg; gate = sigmoid(z);
// o = cl*(1 + gt*(aw-1)); LN. One wave per row; 4 rows per block.
__global__ __launch_bounds__(256) void blendln(
    const float* __restrict__ cl, const short* __restrict__ Z,
    const float* __restrict__ aw, const float* __restrict__ bg,
    const float* __restrict__ gamma, const float* __restrict__ beta,
    float* __restrict__ out)
{
    const int t = threadIdx.x;
    const int lane = t & 63, w = t >> 6;
    const int row = blockIdx.x * 4 + w;
    const float awr = aw[row];
    const long base = (long)row * D_;

    float o[10];
    float s = 0.f, sq = 0.f;
    #pragma unroll
    for (int i = 0; i < 10; ++i) {
        const int col = lane + 64 * i;
        const float y = bf2f(Z[base + col]);
        const float c = cl[base + col];
        const float z = awr * y + bg[col];
        const float gt = 1.f / (1.f + __expf(-z));
        const float ov = c * (1.f + gt * (awr - 1.f));
        o[i] = ov; s += ov; sq += ov * ov;
    }
    s  = wave_reduce_sum(s);
    sq = wave_reduce_sum(sq);
    const float mu  = s * (1.f / D_);
    const float var = sq * (1.f / D_) - mu * mu;
    const float ri  = 1.0f / sqrtf(var + 1e-5f);
    #pragma unroll
    for (int i = 0; i < 10; ++i) {
        const int col = lane + 64 * i;
        out[base + col] = (o[i] - mu) * ri * gamma[col] + beta[col];
    }
}

extern "C" void kernel_launch(void* const* d_in, const int* in_sizes, int n_in,
                              void* d_out, int out_size, void* d_ws, size_t ws_size,
                              hipStream_t stream) {
    const float* clicked_news   = (const float*)d_in[0];   // [B,H,D]
    const float* clicked_topics = (const float*)d_in[1];   // [B,H,Dt]
    const float* cand_topics    = (const float*)d_in[2];   // [B,N,Dt]
    const float* Wq = (const float*)d_in[3];
    const float* bq = (const float*)d_in[4];
    const float* Wk = (const float*)d_in[5];
    const float* bk = (const float*)d_in[6];
    // d_in[7], d_in[8] = Wv, bv: dead code w.r.t. outputs
    const float* Wg = (const float*)d_in[9];
    const float* bg = (const float*)d_in[10];
    const float* ln_gamma = (const float*)d_in[11];
    const float* ln_beta  = (const float*)d_in[12];

    float* out = (float*)d_out;
    float* ws  = (float*)d_ws;

    // ws layout: aw, weights, qss, Qb; Z (half-M, bf16) aliases Qb and
    // extends past it (Qb dead after attn2).
    float* aw   = ws;                                    // B*H floats
    short* Wq_b = (short*)(aw + (long)B_ * H_);          // 163,840
    short* Wk_b = Wq_b + (long)D_ * DT_;                 // 163,840
    short* Wg_b = Wk_b + (long)D_ * DT_;                 // 409,600 row-major [col][k]
    float* qss  = (float*)(Wg_b + (long)D_ * D_);        // B*N*10 floats (640 KB)
    short* Qb   = (short*)(qss + (long)B_ * N_ * 10);    // 10,485,760 shorts
    short* Z    = Qb;                                    // 16,384,000 shorts (aliases Qb+)
    // Kb (bf16) at start of d_out: read by attn2, overwritten by blendln.
    short* Kb = (short*)d_out;
    float* out_tail = out + (long)B_ * H_ * D_;          // attn_weights_agg

    convert3<<<1440, 256, 0, stream>>>(Wq, Wq_b, D_ * DT_,
                                       Wk, Wk_b, D_ * DT_,
                                       Wg, Wg_b, D_ * D_);

    // merged Q-proj (+qss) and K-proj: 1280 + 4000 = 5280 blocks (÷8 ok)
    proj2<<<NQB + NKB, 256, 0, stream>>>(cand_topics, Wq_b, bq, Qb, qss,
                                         clicked_topics, Wk_b, bk, Kb);
    attn2<<<B_, 512, 0, stream>>>(Qb, Kb, qss, aw, out_tail);

    for (int h = 0; h < 2; ++h) {
        const long off = (long)h * MH_;
        // gate GEMM half: 400 x 5 = 2000 blocks (÷8 ok)
        gemm_bt<<<2000, 256, 0, stream>>>(clicked_news + off * D_, D_,
                                          Wg_b, D_, nullptr, Z, 10);
        blendln<<<MH_ / 4, 256, 0, stream>>>(
            clicked_news + off * D_, Z, aw + off, bg, ln_gamma, ln_beta,
            out + off * D_);
    }
}